// Round 15
// baseline (1215.501 us; speedup 1.0000x reference)
//
#include <hip/hip_runtime.h>
#include <stdint.h>

// ---------------- problem constants ----------------
constexpr int TT = 128;    // time steps
constexpr int BB = 256;    // batch
constexpr int LL = 1024;   // hidden dim
constexpr int NG = 4096;   // 4 gates * LL
constexpr int VV = 95;     // vocab

typedef short bf16x8 __attribute__((ext_vector_type(8)));
typedef float f32x4  __attribute__((ext_vector_type(4)));

typedef __attribute__((address_space(1))) const uint32_t gu32;
typedef __attribute__((address_space(3))) uint32_t lu32;

__device__ __forceinline__ unsigned short f2bf(float f) {
    unsigned int u = __builtin_bit_cast(unsigned int, f);
    unsigned int r = (u + 0x7FFFu + ((u >> 16) & 1u)) >> 16;
    return (unsigned short)r;
}
__device__ __forceinline__ float bf2f(unsigned short h) {
    unsigned int u = ((unsigned int)h) << 16;
    return __builtin_bit_cast(float, u);
}
__device__ __forceinline__ float sigmoidf_(float x) {
    return 1.0f / (1.0f + __expf(-x));
}
__device__ __forceinline__ float tanhf_(float x) {
    return 1.0f - 2.0f / (__expf(2.0f * x) + 1.0f);
}

// ---------------- prep: W split (R11 image layout) ----------------
// Recurrent half -> Wimg, per-lt LDS image (131072 B):
//   nl = gate*16 + (l&15); kslot = (k>>3)&3 swizzled by row: kslot' = kslot ^ (nl&3)
//   byte = lt*131072 + (k>>5)*4096 + nl*64 + (kslot'<<4) + (k&7)*2
// Embedding half -> Wemb hi/lo, row-major [row][k], row = lt*64 + nl.
__global__ void prep_w_all(const float* __restrict__ Wf, const float* __restrict__ Wi,
                           const float* __restrict__ Wo, const float* __restrict__ Wc,
                           unsigned short* __restrict__ Wimg,
                           unsigned short* __restrict__ Wemb_hi,
                           unsigned short* __restrict__ Wemb_lo) {
    int idx = blockIdx.x * 256 + threadIdx.x;
    const int total = NG * 2048;  // 8M
    for (; idx < total; idx += gridDim.x * 256) {
        int row = idx >> 11;        // 0..4095
        int col = idx & 2047;       // 0..2047
        int lt   = row >> 6;
        int nl   = row & 63;
        int gate = nl >> 4;
        int l    = lt * 16 + (nl & 15);
        const float* W = (gate == 0) ? Wf : (gate == 1) ? Wi : (gate == 2) ? Wo : Wc;
        float w = W[l * 2048 + col];
        if (col >= 1024) {
            int k = col - 1024;
            int ksl = ((k >> 3) & 3) ^ (nl & 3);
            size_t byte = (size_t)lt * 131072 + (size_t)(k >> 5) * 4096 + nl * 64
                        + (ksl << 4) + (k & 7) * 2;
            *(unsigned short*)((char*)Wimg + byte) = f2bf(w);
        } else {
            unsigned short hi = f2bf(w);
            float lo = w - bf2f(hi);
            Wemb_hi[row * 1024 + col] = hi;
            Wemb_lo[row * 1024 + col] = f2bf(lo);
        }
    }
}

// ---------------- prep: emb hi/lo split, padded to 96 rows ----------------
__global__ void prep_emb_split(const float* __restrict__ emb,
                               unsigned short* __restrict__ Eh,
                               unsigned short* __restrict__ El) {
    int idx = blockIdx.x * 256 + threadIdx.x;   // 96*1024 threads
    int v = idx >> 10;
    float w = (v < VV) ? emb[idx] : 0.0f;
    unsigned short hi = f2bf(w);
    Eh[idx] = hi;
    El[idx] = f2bf(w - bf2f(hi));
}

// ---------------- prep: gate_pre2[v][l][gate] via hi/lo MFMA ----------------
__global__ __launch_bounds__(128)
void gate_pre_mfma(const unsigned short* __restrict__ Eh, const unsigned short* __restrict__ El,
                   const unsigned short* __restrict__ Wh, const unsigned short* __restrict__ Wl,
                   const float* __restrict__ bfv, const float* __restrict__ biv,
                   const float* __restrict__ bov, const float* __restrict__ bcv,
                   float* __restrict__ gp2) {
    const int lt   = blockIdx.x;
    const int tid  = threadIdx.x;
    const int lane = tid & 63;
    const int wm   = tid >> 6;
    const int l15  = lane & 15;
    const int kq   = lane >> 4;          // 0..3

    f32x4 acc[3][4];
    #pragma unroll
    for (int mf = 0; mf < 3; ++mf)
        #pragma unroll
        for (int nf = 0; nf < 4; ++nf) acc[mf][nf] = (f32x4){0.f, 0.f, 0.f, 0.f};

    #pragma unroll 2
    for (int ks = 0; ks < 32; ++ks) {
        const int k0 = ks * 32 + kq * 8;
        bf16x8 ah[3], al[3], bh[4], bl[4];
        #pragma unroll
        for (int mf = 0; mf < 3; ++mf) {
            const size_t ao = (size_t)(wm * 48 + mf * 16 + l15) * 1024 + k0;
            ah[mf] = *(const bf16x8*)(Eh + ao);
            al[mf] = *(const bf16x8*)(El + ao);
        }
        #pragma unroll
        for (int nf = 0; nf < 4; ++nf) {
            const size_t bo = (size_t)(lt * 64 + nf * 16 + l15) * 1024 + k0;
            bh[nf] = *(const bf16x8*)(Wh + bo);
            bl[nf] = *(const bf16x8*)(Wl + bo);
        }
        #pragma unroll
        for (int mf = 0; mf < 3; ++mf)
            #pragma unroll
            for (int nf = 0; nf < 4; ++nf) {
                acc[mf][nf] = __builtin_amdgcn_mfma_f32_16x16x32_bf16(ah[mf], bh[nf], acc[mf][nf], 0, 0, 0);
                acc[mf][nf] = __builtin_amdgcn_mfma_f32_16x16x32_bf16(ah[mf], bl[nf], acc[mf][nf], 0, 0, 0);
                acc[mf][nf] = __builtin_amdgcn_mfma_f32_16x16x32_bf16(al[mf], bh[nf], acc[mf][nf], 0, 0, 0);
            }
    }

    const int lgl = lt * 16 + l15;
    #pragma unroll
    for (int nf = 0; nf < 4; ++nf) {
        const float* bias = (nf == 0) ? bfv : (nf == 1) ? biv : (nf == 2) ? bov : bcv;
        const float bv = bias[lgl];
        #pragma unroll
        for (int mf = 0; mf < 3; ++mf)
            #pragma unroll
            for (int r = 0; r < 4; ++r) {
                const int v = wm * 48 + mf * 16 + kq * 4 + r;
                if (v < VV)
                    gp2[((size_t)v * LL + lgl) * 4 + nf] = acc[mf][nf][r] + bv;
            }
    }
}

// ---------------- prep: init h0 (bf16) and zero sync flags ----------------
__global__ void init_state(const float* __restrict__ h_init,
                           unsigned short* __restrict__ h0,
                           unsigned int* __restrict__ flags) {
    int idx = blockIdx.x * 256 + threadIdx.x;   // 1024*256 = BB*LL
    h0[idx] = f2bf(h_init[idx]);
    if (idx < 4096) flags[idx] = 0;             // packed: flag[bt*64+lt] (dword)
}

// ---------------- persistent LSTM: flag-synced, light-drain epilogue ----------
// grid 256 (bt=blk>>6, lt=blk&63) cooperative, 256 thr = 4 waves.
// K-loop identical to R11 (green, 965us). Epilogue changes only:
//  (1) raw s_barrier instead of __syncthreads (out-stores keep flying),
//  (2) h staged through LDS -> one coalesced global_store_dwordx2 per thread
//      (full 32B sectors; no partial-sector RMW at the coherence point),
//  (3) flags packed at 4B stride (poll touches 4 lines, not 64).
__global__ __launch_bounds__(256, 1)
void lstm_all7(const unsigned short* __restrict__ Wimg,
               const float* __restrict__ gp2,
               const int* __restrict__ x,
               unsigned short* __restrict__ hb0,
               unsigned short* __restrict__ hb1,
               float* __restrict__ out,
               unsigned int* __restrict__ flags) {
    __shared__ unsigned short wlds_s[65536];   // 128 KiB W image
    __shared__ unsigned short hstage[64][24];  // 3 KiB h reshuffle (8B-aligned rows)
    char* wlds = (char*)wlds_s;

    const int tid  = threadIdx.x;
    const int lane = tid & 63;
    const int wv   = tid >> 6;
    const int bt   = blockIdx.x >> 6;
    const int lt   = blockIdx.x & 63;
    const int l15  = lane & 15;
    const int kq   = lane >> 4;

    const int l  = lt * 16 + l15;
    const int b0 = bt * 64 + wv * 16 + kq * 4;

    // ---- stage W into LDS once (linear copy; swizzle baked into image) ----
    {
        const char* wsrc = (const char*)Wimg + (size_t)lt * 131072 + tid * 16;
        #pragma unroll
        for (int j = 0; j < 32; ++j)
            __builtin_amdgcn_global_load_lds((gu32*)(wsrc + j * 4096),
                                             (lu32*)(wlds + j * 4096 + wv * 1024),
                                             16, 0, 0);
        asm volatile("s_waitcnt vmcnt(0)" ::: "memory");
        __syncthreads();
    }
    // swizzled B-frag base: row l15, k-slot kq^(l15&3)
    const char* bbase = wlds + l15 * 64 + ((kq ^ (l15 & 3)) << 4);

    // per-step-invariant addresses
    const size_t arow = (size_t)(bt * 64 + wv * 16 + l15) * 2048 + kq * 16;
    const char* aptr0 = (const char*)hb0 + arow;
    const char* aptr1 = (const char*)hb1 + arow;
    const unsigned int* fpoll = flags + (bt << 6) + lane;   // packed dwords
    const int myflag = (bt << 6) + lt;

    // coalesced h-store mapping: thread -> row tid>>2, 4 l's at (tid&3)*4
    const int sb_bl = tid >> 2;
    const int sb_lq = tid & 3;
    const size_t hso = ((size_t)(bt * 64 + sb_bl) * 1024 + lt * 16 + sb_lq * 4) * 2;

    float c_r[4] = {0.f, 0.f, 0.f, 0.f};
    float* out_t = out;

    #define SB __builtin_amdgcn_sched_barrier(0);

    #define POLLALL()                                                            \
        { unsigned int fv;                                                       \
          for (;;) {                                                             \
            asm volatile("global_load_dword %0, %1, off sc0 sc1\n\t"             \
                         "s_waitcnt vmcnt(0)"                                    \
                         : "=&v"(fv) : "v"(fpoll) : "memory");                   \
            if (__all((int)(fv >= (unsigned int)t))) break;                      \
            __builtin_amdgcn_s_sleep(1);                                         \
          } }

    #define ISSUEA(buf, q)                                                       \
        _Pragma("unroll") for (int ki = 0; ki < 8; ++ki) {                       \
            const char* ap = aptr + ((q) * 8 + ki) * 64;                         \
            asm volatile("global_load_dwordx4 %0, %1, off sc0 sc1"               \
                         : "=&v"(buf[ki]) : "v"(ap));                            \
        }

    #define QCOMP(areg, q)                                                       \
        _Pragma("unroll") for (int ki = 0; ki < 8; ++ki) {                       \
            const int ks = (q) * 8 + ki;                                         \
            const char* bc = bbase + ks * 4096;                                  \
            bf16x8 bw0 = *(const bf16x8*)(bc);                                   \
            bf16x8 bw1 = *(const bf16x8*)(bc + 1024);                            \
            bf16x8 bw2 = *(const bf16x8*)(bc + 2048);                            \
            bf16x8 bw3 = *(const bf16x8*)(bc + 3072);                            \
            acc[0] = __builtin_amdgcn_mfma_f32_16x16x32_bf16(areg[ki], bw0, acc[0], 0, 0, 0); \
            acc[1] = __builtin_amdgcn_mfma_f32_16x16x32_bf16(areg[ki], bw1, acc[1], 0, 0, 0); \
            acc[2] = __builtin_amdgcn_mfma_f32_16x16x32_bf16(areg[ki], bw2, acc[2], 0, 0, 0); \
            acc[3] = __builtin_amdgcn_mfma_f32_16x16x32_bf16(areg[ki], bw3, acc[3], 0, 0, 0); \
        }

    #define WAITV(N) asm volatile("s_waitcnt vmcnt(" #N ")" ::: "memory");

    for (int t = 0; t < TT; ++t) {
        const char* aptr = (t & 1) ? aptr1 : aptr0;
        char* hout = (char*)((t & 1) ? hb0 : hb1);
        const int* xt = x + t * BB;

        f32x4 acc[4];
        #pragma unroll
        for (int nf = 0; nf < 4; ++nf) acc[nf] = (f32x4){0.f, 0.f, 0.f, 0.f};
        bf16x8 bufA[8], bufB[8];

        POLLALL()                              // vm queue empty after this
        SB

        int4 xv;
        {
            const int* xp = xt + b0;
            asm volatile("global_load_dwordx4 %0, %1, off"
                         : "=&v"(xv) : "v"(xp));       // x: read-only, L2 ok
        }
        ISSUEA(bufA, 0)
        ISSUEA(bufB, 1)
        SB
        WAITV(8)                               // x + A0 resident; A1 in flight
        SB
        // gp gather (x now in regs); overlaps Q0..Q2
        float4 gpv[4];
        {
            const int vr[4] = {xv.x, xv.y, xv.z, xv.w};
            #pragma unroll
            for (int r = 0; r < 4; ++r) {
                const float* gpp = gp2 + ((size_t)vr[r] * LL + l) * 4;
                asm volatile("global_load_dwordx4 %0, %1, off"
                             : "=&v"(gpv[r]) : "v"(gpp));
            }
        }
        SB
        QCOMP(bufA, 0) SB
        ISSUEA(bufA, 2) SB
        WAITV(12)                              // A1 done; gp(4)+A2(8) in flight
        SB
        QCOMP(bufB, 1) SB
        ISSUEA(bufB, 3) SB
        WAITV(8)                               // gp+A2 done; A3 in flight
        SB
        QCOMP(bufA, 2) SB
        WAITV(0)                               // A3 done
        SB
        QCOMP(bufB, 3)

        // ---- epilogue: c in regs ----
        float hnew[4];
        #pragma unroll
        for (int r = 0; r < 4; ++r) {
            const float gf = acc[0][r] + gpv[r].x;
            const float gi = acc[1][r] + gpv[r].y;
            const float go = acc[2][r] + gpv[r].z;
            const float gc = acc[3][r] + gpv[r].w;
            const float cn = sigmoidf_(gf) * c_r[r] + sigmoidf_(gi) * tanhf_(gc);
            hnew[r] = sigmoidf_(go) * tanhf_(cn);
            c_r[r] = cn;
        }

        // stage h (bf16) into LDS for coalesced store
        #pragma unroll
        for (int r = 0; r < 4; ++r)
            hstage[wv * 16 + kq * 4 + r][l15] = f2bf(hnew[r]);
        asm volatile("s_waitcnt lgkmcnt(0)" ::: "memory");
        __builtin_amdgcn_s_barrier();          // all hstage writes visible

        // one coalesced 8B h-store per thread (issued FIRST -> oldest in queue)
        {
            uint2 hv = *(const uint2*)&hstage[sb_bl][sb_lq * 4];
            const char* hp = hout + hso;
            asm volatile("global_store_dwordx2 %0, %1, off sc0 sc1"
                         :: "v"(hp), "v"(hv) : "memory");
        }
        // out stores ride behind (never drained before the flag)
        #pragma unroll
        for (int r = 0; r < 4; ++r)
            out_t[(size_t)(b0 + r) * LL + l] = hnew[r];

        WAITV(4)                               // h-store (oldest) done; out in flight
        __builtin_amdgcn_s_barrier();          // raw: no compiler full-drain
        if (tid == 0 && t < TT - 1)
            atomicExch((unsigned int*)&flags[myflag], (unsigned int)(t + 1));
        out_t += BB * LL;
    }

    #undef SB
    #undef POLLALL
    #undef ISSUEA
    #undef QCOMP
    #undef WAITV
}

// ---------------- launch ----------------
extern "C" void kernel_launch(void* const* d_in, const int* in_sizes, int n_in,
                              void* d_out, int out_size, void* d_ws, size_t ws_size,
                              hipStream_t stream) {
    const int*   x      = (const int*)d_in[0];
    const float* h_init = (const float*)d_in[1];
    const float* emb    = (const float*)d_in[2];
    const float* Wf     = (const float*)d_in[3];
    const float* bfv    = (const float*)d_in[4];
    const float* Wi     = (const float*)d_in[5];
    const float* biv    = (const float*)d_in[6];
    const float* Wo     = (const float*)d_in[7];
    const float* bov    = (const float*)d_in[8];
    const float* Wc     = (const float*)d_in[9];
    const float* bcv    = (const float*)d_in[10];
    float* out = (float*)d_out;

    char* ws = (char*)d_ws;
    unsigned short* Wimg    = (unsigned short*)(ws);                 // 8 MB
    unsigned short* Wemb_hi = (unsigned short*)(ws + 8388608);       // 8 MB
    unsigned short* Wemb_lo = (unsigned short*)(ws + 16777216);      // 8 MB
    unsigned short* Eh      = (unsigned short*)(ws + 25165824);      // 192 KB
    unsigned short* El      = (unsigned short*)(ws + 25362432);      // 192 KB
    float*          gp2     = (float*)(ws + 25559040);               // 1.5 MB
    unsigned short* hb0     = (unsigned short*)(ws + 27131904);      // 512 KB
    unsigned short* hb1     = (unsigned short*)(ws + 27656192);      // 512 KB
    unsigned int*   flags   = (unsigned int*)(ws + 28180480);        // 16 KB

    prep_w_all<<<4096, 256, 0, stream>>>(Wf, Wi, Wo, Wc, Wimg, Wemb_hi, Wemb_lo);
    prep_emb_split<<<384, 256, 0, stream>>>(emb, Eh, El);
    gate_pre_mfma<<<64, 128, 0, stream>>>(Eh, El, Wemb_hi, Wemb_lo,
                                          bfv, biv, bov, bcv, gp2);
    init_state<<<1024, 256, 0, stream>>>(h_init, hb0, flags);

    void* kargs[] = {(void*)&Wimg, (void*)&gp2, (void*)&x,
                     (void*)&hb0, (void*)&hb1, (void*)&out, (void*)&flags};
    hipLaunchCooperativeKernel(reinterpret_cast<void*>(lstm_all7),
                               dim3(256), dim3(256), kargs, 0, stream);
}

// Round 17
// 974.047 us; speedup vs baseline: 1.2479x; 1.2479x over previous
//
#include <hip/hip_runtime.h>
#include <stdint.h>

// ---------------- problem constants ----------------
constexpr int TT = 128;    // time steps
constexpr int BB = 256;    // batch
constexpr int LL = 1024;   // hidden dim
constexpr int NG = 4096;   // 4 gates * LL
constexpr int VV = 95;     // vocab

typedef short bf16x8 __attribute__((ext_vector_type(8)));
typedef float f32x4  __attribute__((ext_vector_type(4)));

typedef __attribute__((address_space(1))) const uint32_t gu32;
typedef __attribute__((address_space(3))) uint32_t lu32;

__device__ __forceinline__ unsigned short f2bf(float f) {
    unsigned int u = __builtin_bit_cast(unsigned int, f);
    unsigned int r = (u + 0x7FFFu + ((u >> 16) & 1u)) >> 16;
    return (unsigned short)r;
}
__device__ __forceinline__ float bf2f(unsigned short h) {
    unsigned int u = ((unsigned int)h) << 16;
    return __builtin_bit_cast(float, u);
}
__device__ __forceinline__ float sigmoidf_(float x) {
    return 1.0f / (1.0f + __expf(-x));
}
__device__ __forceinline__ float tanhf_(float x) {
    return 1.0f - 2.0f / (__expf(2.0f * x) + 1.0f);
}

// ---------------- prep: W split (R11 image layout + bank swizzle) ----------------
// Recurrent half -> Wimg, per-lt LDS image (131072 B):
//   nl = gate*16 + (l&15); kslot = (k>>3)&3 swizzled by row: kslot' = kslot ^ (nl&3)
//   byte = lt*131072 + (k>>5)*4096 + nl*64 + (kslot'<<4) + (k&7)*2
// Embedding half -> Wemb hi/lo, row-major [row][k], row = lt*64 + nl.
__global__ void prep_w_all(const float* __restrict__ Wf, const float* __restrict__ Wi,
                           const float* __restrict__ Wo, const float* __restrict__ Wc,
                           unsigned short* __restrict__ Wimg,
                           unsigned short* __restrict__ Wemb_hi,
                           unsigned short* __restrict__ Wemb_lo) {
    int idx = blockIdx.x * 256 + threadIdx.x;
    const int total = NG * 2048;  // 8M
    for (; idx < total; idx += gridDim.x * 256) {
        int row = idx >> 11;        // 0..4095
        int col = idx & 2047;       // 0..2047
        int lt   = row >> 6;
        int nl   = row & 63;
        int gate = nl >> 4;
        int l    = lt * 16 + (nl & 15);
        const float* W = (gate == 0) ? Wf : (gate == 1) ? Wi : (gate == 2) ? Wo : Wc;
        float w = W[l * 2048 + col];
        if (col >= 1024) {
            int k = col - 1024;
            int ksl = ((k >> 3) & 3) ^ (nl & 3);
            size_t byte = (size_t)lt * 131072 + (size_t)(k >> 5) * 4096 + nl * 64
                        + (ksl << 4) + (k & 7) * 2;
            *(unsigned short*)((char*)Wimg + byte) = f2bf(w);
        } else {
            unsigned short hi = f2bf(w);
            float lo = w - bf2f(hi);
            Wemb_hi[row * 1024 + col] = hi;
            Wemb_lo[row * 1024 + col] = f2bf(lo);
        }
    }
}

// ---------------- prep: emb hi/lo split, padded to 96 rows ----------------
__global__ void prep_emb_split(const float* __restrict__ emb,
                               unsigned short* __restrict__ Eh,
                               unsigned short* __restrict__ El) {
    int idx = blockIdx.x * 256 + threadIdx.x;   // 96*1024 threads
    int v = idx >> 10;
    float w = (v < VV) ? emb[idx] : 0.0f;
    unsigned short hi = f2bf(w);
    Eh[idx] = hi;
    El[idx] = f2bf(w - bf2f(hi));
}

// ---------------- prep: gate_pre2[v][l][gate] via hi/lo MFMA ----------------
__global__ __launch_bounds__(128)
void gate_pre_mfma(const unsigned short* __restrict__ Eh, const unsigned short* __restrict__ El,
                   const unsigned short* __restrict__ Wh, const unsigned short* __restrict__ Wl,
                   const float* __restrict__ bfv, const float* __restrict__ biv,
                   const float* __restrict__ bov, const float* __restrict__ bcv,
                   float* __restrict__ gp2) {
    const int lt   = blockIdx.x;
    const int tid  = threadIdx.x;
    const int lane = tid & 63;
    const int wm   = tid >> 6;
    const int l15  = lane & 15;
    const int kq   = lane >> 4;          // 0..3

    f32x4 acc[3][4];
    #pragma unroll
    for (int mf = 0; mf < 3; ++mf)
        #pragma unroll
        for (int nf = 0; nf < 4; ++nf) acc[mf][nf] = (f32x4){0.f, 0.f, 0.f, 0.f};

    #pragma unroll 2
    for (int ks = 0; ks < 32; ++ks) {
        const int k0 = ks * 32 + kq * 8;
        bf16x8 ah[3], al[3], bh[4], bl[4];
        #pragma unroll
        for (int mf = 0; mf < 3; ++mf) {
            const size_t ao = (size_t)(wm * 48 + mf * 16 + l15) * 1024 + k0;
            ah[mf] = *(const bf16x8*)(Eh + ao);
            al[mf] = *(const bf16x8*)(El + ao);
        }
        #pragma unroll
        for (int nf = 0; nf < 4; ++nf) {
            const size_t bo = (size_t)(lt * 64 + nf * 16 + l15) * 1024 + k0;
            bh[nf] = *(const bf16x8*)(Wh + bo);
            bl[nf] = *(const bf16x8*)(Wl + bo);
        }
        #pragma unroll
        for (int mf = 0; mf < 3; ++mf)
            #pragma unroll
            for (int nf = 0; nf < 4; ++nf) {
                acc[mf][nf] = __builtin_amdgcn_mfma_f32_16x16x32_bf16(ah[mf], bh[nf], acc[mf][nf], 0, 0, 0);
                acc[mf][nf] = __builtin_amdgcn_mfma_f32_16x16x32_bf16(ah[mf], bl[nf], acc[mf][nf], 0, 0, 0);
                acc[mf][nf] = __builtin_amdgcn_mfma_f32_16x16x32_bf16(al[mf], bh[nf], acc[mf][nf], 0, 0, 0);
            }
    }

    const int lgl = lt * 16 + l15;
    #pragma unroll
    for (int nf = 0; nf < 4; ++nf) {
        const float* bias = (nf == 0) ? bfv : (nf == 1) ? biv : (nf == 2) ? bov : bcv;
        const float bv = bias[lgl];
        #pragma unroll
        for (int mf = 0; mf < 3; ++mf)
            #pragma unroll
            for (int r = 0; r < 4; ++r) {
                const int v = wm * 48 + mf * 16 + kq * 4 + r;
                if (v < VV)
                    gp2[((size_t)v * LL + lgl) * 4 + nf] = acc[mf][nf][r] + bv;
            }
    }
}

// ---------------- prep: init h0 (bf16) and zero sync flags ----------------
__global__ void init_state(const float* __restrict__ h_init,
                           unsigned short* __restrict__ h0,
                           unsigned int* __restrict__ flags) {
    int idx = blockIdx.x * 256 + threadIdx.x;   // 1024*256 = BB*LL
    h0[idx] = f2bf(h_init[idx]);
    if (idx < 4096) flags[idx] = 0;             // 256 block-flags, 64B-strided
}

// ---------------- persistent LSTM, flag-synced, conflict-free, 1 poll/step ----
// grid 256 (bt=blk>>6, lt=blk&63) cooperative, 256 thr = 4 waves.
// W LDS-resident (swizzled) for all 128 steps; c in registers; barrier-free
// K-loop with counted vmcnt; single 64-flag poll per step.
// All inline-asm load dests are EARLY-CLOBBER ("=&v"): without it the allocator
// may alias the dest with the (long-lived) address pair -> garbage address on
// the next poll/step -> page fault (R10 crash).
__global__ __launch_bounds__(256, 1)
void lstm_all3(const unsigned short* __restrict__ Wimg,
               const float* __restrict__ gp2,
               const int* __restrict__ x,
               unsigned short* __restrict__ hb0,
               unsigned short* __restrict__ hb1,
               float* __restrict__ out,
               unsigned int* __restrict__ flags) {
    __shared__ unsigned short wlds_s[65536];   // 128 KiB
    char* wlds = (char*)wlds_s;

    const int tid  = threadIdx.x;
    const int lane = tid & 63;
    const int wv   = tid >> 6;
    const int bt   = blockIdx.x >> 6;
    const int lt   = blockIdx.x & 63;
    const int l15  = lane & 15;
    const int kq   = lane >> 4;

    const int l  = lt * 16 + l15;
    const int b0 = bt * 64 + wv * 16 + kq * 4;

    // ---- stage W into LDS once (linear copy; swizzle baked into image) ----
    {
        const char* wsrc = (const char*)Wimg + (size_t)lt * 131072 + tid * 16;
        #pragma unroll
        for (int j = 0; j < 32; ++j)
            __builtin_amdgcn_global_load_lds((gu32*)(wsrc + j * 4096),
                                             (lu32*)(wlds + j * 4096 + wv * 1024),
                                             16, 0, 0);
        asm volatile("s_waitcnt vmcnt(0)" ::: "memory");
        __syncthreads();
    }
    // swizzled B-frag base: row l15, k-slot kq^(l15&3)
    const char* bbase = wlds + l15 * 64 + ((kq ^ (l15 & 3)) << 4);

    // per-step-invariant addresses
    const size_t arow = (size_t)(bt * 64 + wv * 16 + l15) * 2048 + kq * 16;
    const char* aptr0 = (const char*)hb0 + arow;
    const char* aptr1 = (const char*)hb1 + arow;
    const unsigned int* fpoll = flags + (((bt << 6) + lane) << 4);  // lane -> producer lt
    const int myflag = ((bt << 6) + lt) << 4;

    float c_r[4] = {0.f, 0.f, 0.f, 0.f};
    float* out_t = out;

    #define SB __builtin_amdgcn_sched_barrier(0);

    #define POLLALL()                                                            \
        { unsigned int fv;                                                       \
          for (;;) {                                                             \
            asm volatile("global_load_dword %0, %1, off sc0 sc1\n\t"             \
                         "s_waitcnt vmcnt(0)"                                    \
                         : "=&v"(fv) : "v"(fpoll) : "memory");                   \
            if (__all((int)(fv >= (unsigned int)t))) break;                      \
            __builtin_amdgcn_s_sleep(1);                                         \
          } }

    #define ISSUEA(buf, q)                                                       \
        _Pragma("unroll") for (int ki = 0; ki < 8; ++ki) {                       \
            const char* ap = aptr + ((q) * 8 + ki) * 64;                         \
            asm volatile("global_load_dwordx4 %0, %1, off sc0 sc1"               \
                         : "=&v"(buf[ki]) : "v"(ap));                            \
        }

    #define QCOMP(areg, q)                                                       \
        _Pragma("unroll") for (int ki = 0; ki < 8; ++ki) {                       \
            const int ks = (q) * 8 + ki;                                         \
            const char* bc = bbase + ks * 4096;                                  \
            bf16x8 bw0 = *(const bf16x8*)(bc);                                   \
            bf16x8 bw1 = *(const bf16x8*)(bc + 1024);                            \
            bf16x8 bw2 = *(const bf16x8*)(bc + 2048);                            \
            bf16x8 bw3 = *(const bf16x8*)(bc + 3072);                            \
            acc[0] = __builtin_amdgcn_mfma_f32_16x16x32_bf16(areg[ki], bw0, acc[0], 0, 0, 0); \
            acc[1] = __builtin_amdgcn_mfma_f32_16x16x32_bf16(areg[ki], bw1, acc[1], 0, 0, 0); \
            acc[2] = __builtin_amdgcn_mfma_f32_16x16x32_bf16(areg[ki], bw2, acc[2], 0, 0, 0); \
            acc[3] = __builtin_amdgcn_mfma_f32_16x16x32_bf16(areg[ki], bw3, acc[3], 0, 0, 0); \
        }

    #define WAITV(N) asm volatile("s_waitcnt vmcnt(" #N ")" ::: "memory");

    for (int t = 0; t < TT; ++t) {
        const char* aptr = (t & 1) ? aptr1 : aptr0;
        unsigned short* hout = (t & 1) ? hb0 : hb1;
        const int* xt = x + t * BB;

        f32x4 acc[4];
        #pragma unroll
        for (int nf = 0; nf < 4; ++nf) acc[nf] = (f32x4){0.f, 0.f, 0.f, 0.f};
        bf16x8 bufA[8], bufB[8];

        POLLALL()                              // vm queue empty after this
        SB

        int4 xv;
        {
            const int* xp = xt + b0;
            asm volatile("global_load_dwordx4 %0, %1, off"
                         : "=&v"(xv) : "v"(xp));       // x: read-only, L2 ok
        }
        ISSUEA(bufA, 0)
        ISSUEA(bufB, 1)
        SB
        WAITV(8)                               // x + A0 resident; A1 in flight
        SB
        // gp gather (x now in regs); overlaps Q0..Q2
        float4 gpv[4];
        {
            const int vr[4] = {xv.x, xv.y, xv.z, xv.w};
            #pragma unroll
            for (int r = 0; r < 4; ++r) {
                const float* gpp = gp2 + ((size_t)vr[r] * LL + l) * 4;
                asm volatile("global_load_dwordx4 %0, %1, off"
                             : "=&v"(gpv[r]) : "v"(gpp));
            }
        }
        SB
        QCOMP(bufA, 0) SB
        ISSUEA(bufA, 2) SB
        WAITV(12)                              // A1 done; gp(4)+A2(8) in flight
        SB
        QCOMP(bufB, 1) SB
        ISSUEA(bufB, 3) SB
        WAITV(8)                               // gp+A2 done; A3 in flight
        SB
        QCOMP(bufA, 2) SB
        WAITV(0)                               // A3 done
        SB
        QCOMP(bufB, 3)

        // ---- epilogue: c in regs; h write-through first, out rides the queue ----
        float hnew[4];
        #pragma unroll
        for (int r = 0; r < 4; ++r) {
            const float gf = acc[0][r] + gpv[r].x;
            const float gi = acc[1][r] + gpv[r].y;
            const float go = acc[2][r] + gpv[r].z;
            const float gc = acc[3][r] + gpv[r].w;
            const float cn = sigmoidf_(gf) * c_r[r] + sigmoidf_(gi) * tanhf_(gc);
            hnew[r] = sigmoidf_(go) * tanhf_(cn);
            c_r[r] = cn;
        }
        #pragma unroll
        for (int r = 0; r < 4; ++r) {
            const size_t off = (size_t)(b0 + r) * LL + l;
            unsigned int hbits = f2bf(hnew[r]);
            const unsigned short* hp = hout + off;
            asm volatile("global_store_short %0, %1, off sc0 sc1"
                         :: "v"(hp), "v"(hbits) : "memory");
        }
        #pragma unroll
        for (int r = 0; r < 4; ++r)
            out_t[(size_t)(b0 + r) * LL + l] = hnew[r];

        WAITV(4)                               // h stores done; out still in flight
        __syncthreads();
        if (tid == 0 && t < TT - 1)
            atomicExch(&flags[myflag], (unsigned int)(t + 1));
        out_t += BB * LL;
    }

    #undef SB
    #undef POLLALL
    #undef ISSUEA
    #undef QCOMP
    #undef WAITV
}

// ---------------- launch ----------------
extern "C" void kernel_launch(void* const* d_in, const int* in_sizes, int n_in,
                              void* d_out, int out_size, void* d_ws, size_t ws_size,
                              hipStream_t stream) {
    const int*   x      = (const int*)d_in[0];
    const float* h_init = (const float*)d_in[1];
    const float* emb    = (const float*)d_in[2];
    const float* Wf     = (const float*)d_in[3];
    const float* bfv    = (const float*)d_in[4];
    const float* Wi     = (const float*)d_in[5];
    const float* biv    = (const float*)d_in[6];
    const float* Wo     = (const float*)d_in[7];
    const float* bov    = (const float*)d_in[8];
    const float* Wc     = (const float*)d_in[9];
    const float* bcv    = (const float*)d_in[10];
    float* out = (float*)d_out;

    char* ws = (char*)d_ws;
    unsigned short* Wimg    = (unsigned short*)(ws);                 // 8 MB
    unsigned short* Wemb_hi = (unsigned short*)(ws + 8388608);       // 8 MB
    unsigned short* Wemb_lo = (unsigned short*)(ws + 16777216);      // 8 MB
    unsigned short* Eh      = (unsigned short*)(ws + 25165824);      // 192 KB
    unsigned short* El      = (unsigned short*)(ws + 25362432);      // 192 KB
    float*          gp2     = (float*)(ws + 25559040);               // 1.5 MB
    unsigned short* hb0     = (unsigned short*)(ws + 27131904);      // 512 KB
    unsigned short* hb1     = (unsigned short*)(ws + 27656192);      // 512 KB
    unsigned int*   flags   = (unsigned int*)(ws + 28180480);        // 16 KB

    prep_w_all<<<4096, 256, 0, stream>>>(Wf, Wi, Wo, Wc, Wimg, Wemb_hi, Wemb_lo);
    prep_emb_split<<<384, 256, 0, stream>>>(emb, Eh, El);
    gate_pre_mfma<<<64, 128, 0, stream>>>(Eh, El, Wemb_hi, Wemb_lo,
                                          bfv, biv, bov, bcv, gp2);
    init_state<<<1024, 256, 0, stream>>>(h_init, hb0, flags);

    void* kargs[] = {(void*)&Wimg, (void*)&gp2, (void*)&x,
                     (void*)&hb0, (void*)&hb1, (void*)&out, (void*)&flags};
    hipLaunchCooperativeKernel(reinterpret_cast<void*>(lstm_all3),
                               dim3(256), dim3(256), kargs, 0, stream);
}